// Round 1
// baseline (359.410 us; speedup 1.0000x reference)
//
#include <hip/hip_runtime.h>
#include <cstddef>

#define Bq   64
#define Sq   512
#define Pq   32
#define Lq   30
#define Hq   768
#define Mq   2048      // B*P
#define N1q  1024      // FH
#define N2q  512       // FH/2

// ---------------- GEMM1: feat(gathered) @ W1 -> C1 partials (split-K z=4) ---
// BM=BN=128, BK=16, 256 threads, 8x8 micro-tile. z=0,1: token half (k<768),
// z=2,3: pooler half. Each z writes its own partial buffer (deterministic).
__global__ __launch_bounds__(256)
void gemm1_kernel(const float* __restrict__ tok, const float* __restrict__ pool,
                  const int* __restrict__ npos, const float* __restrict__ W1,
                  float* __restrict__ C1part) {
  const int bz = blockIdx.z;           // k range [bz*384, bz*384+384)
  const int n0 = blockIdx.x * 128;
  const int m0 = blockIdx.y * 128;
  const int tid = threadIdx.x;

  __shared__ float As[16][132];        // transposed A tile, padded stride
  __shared__ float Bs[16][128];

  const int arow = tid >> 1;           // 0..127
  const int akh  = (tid & 1) * 8;      // 0 or 8
  const int m    = m0 + arow;
  const int bI   = m >> 5;
  const int p    = m & 31;
  const int ksrc = bz * 384;
  const float* aBase;
  if (bz < 2) {
    const int pos = npos[bI * Pq + p];
    aBase = tok + ((size_t)bI * Sq + pos) * Hq + ksrc;
  } else {
    aBase = pool + (size_t)bI * Hq + (ksrc - Hq);
  }

  const int bk = tid >> 4;             // 0..15
  const int bn = (tid & 15) * 8;       // 0..120
  const float* bBase = W1 + (size_t)(ksrc + bk) * N1q + n0 + bn;

  float acc[8][8];
  #pragma unroll
  for (int i = 0; i < 8; ++i)
    #pragma unroll
    for (int j = 0; j < 8; ++j) acc[i][j] = 0.f;

  const int tx = tid & 15, ty = tid >> 4;

  for (int kt = 0; kt < 384; kt += 16) {
    float4 a0 = *(const float4*)(aBase + kt + akh);
    float4 a1 = *(const float4*)(aBase + kt + akh + 4);
    float4 b0 = *(const float4*)(bBase + (size_t)kt * N1q);
    float4 b1 = *(const float4*)(bBase + (size_t)kt * N1q + 4);
    __syncthreads();
    As[akh+0][arow] = a0.x; As[akh+1][arow] = a0.y;
    As[akh+2][arow] = a0.z; As[akh+3][arow] = a0.w;
    As[akh+4][arow] = a1.x; As[akh+5][arow] = a1.y;
    As[akh+6][arow] = a1.z; As[akh+7][arow] = a1.w;
    *(float4*)&Bs[bk][bn]     = b0;
    *(float4*)&Bs[bk][bn + 4] = b1;
    __syncthreads();
    #pragma unroll
    for (int k = 0; k < 16; ++k) {
      float4 aA = *(const float4*)&As[k][ty*8];
      float4 aB = *(const float4*)&As[k][ty*8+4];
      float4 bA = *(const float4*)&Bs[k][tx*8];
      float4 bB = *(const float4*)&Bs[k][tx*8+4];
      float av[8] = {aA.x,aA.y,aA.z,aA.w,aB.x,aB.y,aB.z,aB.w};
      float bv[8] = {bA.x,bA.y,bA.z,bA.w,bB.x,bB.y,bB.z,bB.w};
      #pragma unroll
      for (int i = 0; i < 8; ++i)
        #pragma unroll
        for (int j = 0; j < 8; ++j)
          acc[i][j] = fmaf(av[i], bv[j], acc[i][j]);
    }
  }

  float* Cp = C1part + (size_t)bz * Mq * N1q;
  #pragma unroll
  for (int i = 0; i < 8; ++i) {
    float4 v0 = {acc[i][0],acc[i][1],acc[i][2],acc[i][3]};
    float4 v1 = {acc[i][4],acc[i][5],acc[i][6],acc[i][7]};
    float* dst = Cp + (size_t)(m0 + ty*8 + i) * N1q + n0 + tx*8;
    *(float4*)dst = v0;
    *(float4*)(dst+4) = v1;
  }
}

// ---------------- GEMM2: (sum C1 partials + b1) @ W2 -> C2 partials (z=4) ---
__global__ __launch_bounds__(256)
void gemm2_kernel(const float* __restrict__ C1, const float* __restrict__ b1,
                  const float* __restrict__ W2, float* __restrict__ C2part) {
  const int bz = blockIdx.z;           // k range [bz*256, +256)
  const int n0 = blockIdx.x * 128;
  const int m0 = blockIdx.y * 128;
  const int tid = threadIdx.x;

  __shared__ float As[16][132];
  __shared__ float Bs[16][128];

  const int arow = tid >> 1;
  const int akh  = (tid & 1) * 8;
  const int m    = m0 + arow;
  const int kg0  = bz * 256;
  const size_t MN1 = (size_t)Mq * N1q;
  const float* a0p = C1 + (size_t)m * N1q + kg0 + akh;

  const int bk = tid >> 4;
  const int bn = (tid & 15) * 8;
  const float* bBase = W2 + (size_t)(kg0 + bk) * N2q + n0 + bn;

  float acc[8][8];
  #pragma unroll
  for (int i = 0; i < 8; ++i)
    #pragma unroll
    for (int j = 0; j < 8; ++j) acc[i][j] = 0.f;

  const int tx = tid & 15, ty = tid >> 4;

  for (int kt = 0; kt < 256; kt += 16) {
    float4 s0 = *(const float4*)(b1 + kg0 + akh + kt);
    float4 s1 = *(const float4*)(b1 + kg0 + akh + kt + 4);
    #pragma unroll
    for (int s = 0; s < 4; ++s) {
      float4 x0 = *(const float4*)(a0p + s*MN1 + kt);
      float4 x1 = *(const float4*)(a0p + s*MN1 + kt + 4);
      s0.x += x0.x; s0.y += x0.y; s0.z += x0.z; s0.w += x0.w;
      s1.x += x1.x; s1.y += x1.y; s1.z += x1.z; s1.w += x1.w;
    }
    float4 b0  = *(const float4*)(bBase + (size_t)kt * N2q);
    float4 b1v = *(const float4*)(bBase + (size_t)kt * N2q + 4);
    __syncthreads();
    As[akh+0][arow] = s0.x; As[akh+1][arow] = s0.y;
    As[akh+2][arow] = s0.z; As[akh+3][arow] = s0.w;
    As[akh+4][arow] = s1.x; As[akh+5][arow] = s1.y;
    As[akh+6][arow] = s1.z; As[akh+7][arow] = s1.w;
    *(float4*)&Bs[bk][bn]     = b0;
    *(float4*)&Bs[bk][bn + 4] = b1v;
    __syncthreads();
    #pragma unroll
    for (int k = 0; k < 16; ++k) {
      float4 aA = *(const float4*)&As[k][ty*8];
      float4 aB = *(const float4*)&As[k][ty*8+4];
      float4 bA = *(const float4*)&Bs[k][tx*8];
      float4 bB = *(const float4*)&Bs[k][tx*8+4];
      float av[8] = {aA.x,aA.y,aA.z,aA.w,aB.x,aB.y,aB.z,aB.w};
      float bv[8] = {bA.x,bA.y,bA.z,bA.w,bB.x,bB.y,bB.z,bB.w};
      #pragma unroll
      for (int i = 0; i < 8; ++i)
        #pragma unroll
        for (int j = 0; j < 8; ++j)
          acc[i][j] = fmaf(av[i], bv[j], acc[i][j]);
    }
  }

  float* Cp = C2part + (size_t)bz * Mq * N2q;
  #pragma unroll
  for (int i = 0; i < 8; ++i) {
    float4 v0 = {acc[i][0],acc[i][1],acc[i][2],acc[i][3]};
    float4 v1 = {acc[i][4],acc[i][5],acc[i][6],acc[i][7]};
    float* dst = Cp + (size_t)(m0 + ty*8 + i) * N2q + n0 + tx*8;
    *(float4*)dst = v0;
    *(float4*)(dst+4) = v1;
  }
}

// ---------------- logits + fused loss: one wave per slot m ------------------
__global__ __launch_bounds__(256)
void loss_kernel(const float* __restrict__ C2, const float* __restrict__ b2,
                 const float* __restrict__ W3, const float* __restrict__ b3,
                 const float* __restrict__ labels, float* __restrict__ acc) {
  __shared__ float hs[4][512];
  const int tid  = threadIdx.x;
  const int wave = tid >> 6;
  const int lane = tid & 63;
  const int m    = blockIdx.x * 4 + wave;
  const size_t MN2 = (size_t)Mq * N2q;

  // h[m][k] = sum_s C2part[s][m][k] + b2[k]
  #pragma unroll
  for (int j = 0; j < 8; ++j) {
    const int k = lane + 64*j;
    float v = b2[k];
    #pragma unroll
    for (int s = 0; s < 4; ++s) v += C2[s*MN2 + (size_t)m*N2q + k];
    hs[wave][k] = v;
  }
  __syncthreads();

  const bool act = lane < Lq;
  float logit = 0.f, lab = 0.f;
  if (act) {
    logit = b3[lane];
    const float* hp = hs[wave];
    #pragma unroll 8
    for (int k = 0; k < 512; ++k)
      logit = fmaf(hp[k], W3[k*Lq + lane], logit);
    lab = labels[(size_t)m * Lq + lane];
  }

  const unsigned long long validmask = __ballot(act && lab != -1.0f);
  const unsigned long long outmask   = __ballot(act && logit > 0.0f);
  const unsigned long long labmask   = __ballot(act && lab == 1.0f);
  const bool valid = (validmask != 0ULL);
  const int count_out = __popcll(outmask);
  const int count_lab = __popcll(labmask);

  float bce = 0.f;
  if (act && valid) {
    const float x = logit;
    bce = fmaxf(x, 0.f) + log1pf(expf(-fabsf(x))) - x * lab;
  }
  #pragma unroll
  for (int off = 32; off > 0; off >>= 1) bce += __shfl_xor(bce, off);

  if (lane == 0) {
    if (valid) {
      atomicAdd(&acc[0], bce);           // bce numerator sum
      atomicAdd(&acc[1], 1.0f);          // mf sum (valid slot count)
      const float d = (float)count_out - (float)count_lab;
      atomicAdd(&acc[2], d * d);         // count-loss numerator
    }
    if (count_out == 1 && count_lab == 1) {
      const float po = (float)(__ffsll((long long)outmask) - 1);
      const float pl = (float)(__ffsll((long long)labmask) - 1);
      atomicAdd(&acc[3], 1.0f);          // n_eq
      const float dp = po - pl;
      atomicAdd(&acc[4], dp * dp);       // pos-loss numerator
    }
  }
}

__global__ void clear_acc(float* acc) {
  if (threadIdx.x < 8) acc[threadIdx.x] = 0.f;
}

__global__ void finalize_kernel(const float* __restrict__ acc,
                                float* __restrict__ out) {
  const float bce = acc[0] / (acc[1] * (float)Lq);
  const float cnt = 10.0f * acc[2] / (float)Mq;
  const float pos = (acc[3] > 0.f) ? 5.0f * acc[4] / fmaxf(acc[3], 1.0f) : 0.f;
  out[0] = bce + cnt + pos;
}

extern "C" void kernel_launch(void* const* d_in, const int* in_sizes, int n_in,
                              void* d_out, int out_size, void* d_ws, size_t ws_size,
                              hipStream_t stream) {
  const float* tok    = (const float*)d_in[0];
  const float* pool   = (const float*)d_in[1];
  const int*   npos   = (const int*)  d_in[2];
  const float* labels = (const float*)d_in[3];
  const float* W1     = (const float*)d_in[4];
  const float* b1     = (const float*)d_in[5];
  const float* W2     = (const float*)d_in[6];
  const float* b2     = (const float*)d_in[7];
  const float* W3     = (const float*)d_in[8];
  const float* b3     = (const float*)d_in[9];
  float* out = (float*)d_out;

  char* ws = (char*)d_ws;
  float* C1  = (float*)ws;                                        // 4*2048*1024 f32 = 32 MB
  float* C2  = (float*)(ws + 4 * (size_t)Mq * N1q * sizeof(float)); // 4*2048*512 f32 = 16 MB
  float* acc = (float*)(ws + 4 * (size_t)Mq * N1q * sizeof(float)
                           + 4 * (size_t)Mq * N2q * sizeof(float));

  clear_acc<<<1, 64, 0, stream>>>(acc);
  gemm1_kernel<<<dim3(8, 16, 4), 256, 0, stream>>>(tok, pool, npos, W1, C1);
  gemm2_kernel<<<dim3(4, 16, 4), 256, 0, stream>>>(C1, b1, W2, C2);
  loss_kernel<<<512, 256, 0, stream>>>(C2, b2, W3, b3, labels, acc);
  finalize_kernel<<<1, 1, 0, stream>>>(acc, out);
}

// Round 2
// 256.173 us; speedup vs baseline: 1.4030x; 1.4030x over previous
//
#include <hip/hip_runtime.h>
#include <cstddef>
#include <cstdint>

#define Mq   2048      // B*P
#define Lq   30
#define N1q  1024      // FH
#define N2q  512       // FH/2
#define K1q  1536      // 2*H
#define Hq   768

typedef float    f32x4 __attribute__((ext_vector_type(4)));
typedef _Float16 f16x8 __attribute__((ext_vector_type(8)));

#define GLD16(gptr, lptr) \
  __builtin_amdgcn_global_load_lds((const __attribute__((address_space(1))) void*)(gptr), \
                                   (__attribute__((address_space(3))) void*)(lptr), 16, 0, 0)

// ---------- prep: gather token rows + pooler -> A1 fp16 [2048][1536]; clear acc
__global__ __launch_bounds__(256)
void prep_a1(const float* __restrict__ tok, const float* __restrict__ pool,
             const int* __restrict__ npos, _Float16* __restrict__ A1,
             float* __restrict__ acc) {
  const int m = blockIdx.x;
  const int bI = m >> 5, p = m & 31;
  if (m == 0 && threadIdx.x < 8) acc[threadIdx.x] = 0.f;
  const int pos = npos[bI * 32 + p];
  const float* src1 = tok + ((size_t)bI * 512 + pos) * Hq;
  const float* src2 = pool + (size_t)bI * Hq;
  _Float16* dst = A1 + (size_t)m * K1q;
  for (int g = threadIdx.x; g < 384; g += 256) {
    const float* s = (g < 192) ? (src1 + g * 4) : (src2 + (g - 192) * 4);
    float4 v = *(const float4*)s;
    __align__(8) _Float16 o[4] = {(_Float16)v.x, (_Float16)v.y, (_Float16)v.z, (_Float16)v.w};
    *(uint2*)(dst + g * 4) = *(const uint2*)o;
  }
}

// ---------- transpose + convert: src f32 [K][N] -> dst f16 [N][K]
template<int K, int N>
__global__ __launch_bounds__(256)
void transpose_cvt(const float* __restrict__ src, _Float16* __restrict__ dst) {
  __shared__ float T[64][65];
  const int t = threadIdx.x;
  const int n0 = blockIdx.x * 64, k0 = blockIdx.y * 64;
  {
    const int kl = t >> 2, nc = (t & 3) * 16;
    const float* s = src + (size_t)(k0 + kl) * N + n0 + nc;
    float4 v0 = *(const float4*)s;
    float4 v1 = *(const float4*)(s + 4);
    float4 v2 = *(const float4*)(s + 8);
    float4 v3 = *(const float4*)(s + 12);
    T[nc + 0][kl] = v0.x; T[nc + 1][kl] = v0.y; T[nc + 2][kl] = v0.z; T[nc + 3][kl] = v0.w;
    T[nc + 4][kl] = v1.x; T[nc + 5][kl] = v1.y; T[nc + 6][kl] = v1.z; T[nc + 7][kl] = v1.w;
    T[nc + 8][kl] = v2.x; T[nc + 9][kl] = v2.y; T[nc +10][kl] = v2.z; T[nc +11][kl] = v2.w;
    T[nc +12][kl] = v3.x; T[nc +13][kl] = v3.y; T[nc +14][kl] = v3.z; T[nc +15][kl] = v3.w;
  }
  __syncthreads();
  {
    const int nl = t >> 2, kc = (t & 3) * 16;
    __align__(16) _Float16 tmp[16];
    #pragma unroll
    for (int i = 0; i < 16; ++i) tmp[i] = (_Float16)T[nl][kc + i];
    _Float16* d = dst + (size_t)(n0 + nl) * K + k0 + kc;
    *(uint4*)d       = *(const uint4*)tmp;
    *(uint4*)(d + 8) = *(const uint4*)(tmp + 8);
  }
}

// ---------- MFMA GEMM: A f16 [2048][KFULL] @ BT f16 [NC][KFULL] -> fp32 partials
// 128x128 tile, BK=32, 4 waves (2x2 of 64x64), 16x16x32 f16 MFMA, split-K by z.
// LDS layout: [row][32k] with 16B-chunk XOR swizzle c ^= (row>>1)&3 applied on
// the GLOBAL source address (global_load_lds dest is wave-base + lane*16).
template<int KFULL, int KSLICE, int NC>
__global__ __launch_bounds__(256)
void gemm_f16(const _Float16* __restrict__ A, const _Float16* __restrict__ BT,
              float* __restrict__ Cpart) {
  __shared__ _Float16 As[128 * 32];
  __shared__ _Float16 Bs[128 * 32];
  const int tid = threadIdx.x, w = tid >> 6, lane = tid & 63;
  const int n0 = blockIdx.x * 128, m0 = blockIdx.y * 128, z = blockIdx.z;
  const int ml = lane & 15, g4 = lane >> 4;
  const int wm = (w >> 1) * 64, wn = (w & 1) * 64;

  f32x4 acc[4][4];
  #pragma unroll
  for (int i = 0; i < 4; ++i)
    #pragma unroll
    for (int j = 0; j < 4; ++j)
      #pragma unroll
      for (int r = 0; r < 4; ++r) acc[i][j][r] = 0.f;

  const int rs0 = w * 32 + (lane >> 2);   // staging row (t=0); t=1 adds 16
  const int cl  = lane & 3;               // staging chunk slot within row

  for (int it = 0; it < KSLICE / 32; ++it) {
    const int kt = z * KSLICE + it * 32;
    __syncthreads();
    #pragma unroll
    for (int t = 0; t < 2; ++t) {
      const int r  = rs0 + t * 16;
      const int cs = cl ^ ((r >> 1) & 3);
      GLD16(A  + (size_t)(m0 + r) * KFULL + kt + cs * 8, As + (w * 32 + t * 16) * 32);
      GLD16(BT + (size_t)(n0 + r) * KFULL + kt + cs * 8, Bs + (w * 32 + t * 16) * 32);
    }
    __syncthreads();
    f16x8 af[4], bf[4];
    #pragma unroll
    for (int i = 0; i < 4; ++i) {
      const int ar = wm + i * 16 + ml;
      af[i] = *(const f16x8*)(As + ar * 32 + ((g4 ^ ((ar >> 1) & 3)) << 3));
      const int br = wn + i * 16 + ml;
      bf[i] = *(const f16x8*)(Bs + br * 32 + ((g4 ^ ((br >> 1) & 3)) << 3));
    }
    #pragma unroll
    for (int i = 0; i < 4; ++i)
      #pragma unroll
      for (int j = 0; j < 4; ++j)
        acc[i][j] = __builtin_amdgcn_mfma_f32_16x16x32_f16(af[i], bf[j], acc[i][j], 0, 0, 0);
  }

  float* Cp = Cpart + (size_t)z * Mq * NC;
  #pragma unroll
  for (int i = 0; i < 4; ++i) {
    const int row0 = m0 + wm + i * 16 + g4 * 4;
    #pragma unroll
    for (int j = 0; j < 4; ++j) {
      const int col = n0 + wn + j * 16 + ml;
      #pragma unroll
      for (int r = 0; r < 4; ++r)
        Cp[(size_t)(row0 + r) * NC + col] = acc[i][j][r];
    }
  }
}

// ---------- combine1: h1 = f16(p0 + p1 + b1)   [2048][1024]
__global__ __launch_bounds__(256)
void combine1(const float* __restrict__ P, const float* __restrict__ b1,
              _Float16* __restrict__ h1) {
  const int idx = (blockIdx.x * 256 + threadIdx.x) * 4;
  const int col = idx & (N1q - 1);
  const size_t MN = (size_t)Mq * N1q;
  float4 v = *(const float4*)(P + idx);
  float4 u = *(const float4*)(P + MN + idx);
  float4 b = *(const float4*)(b1 + col);
  __align__(8) _Float16 o[4] = {
      (_Float16)(v.x + u.x + b.x), (_Float16)(v.y + u.y + b.y),
      (_Float16)(v.z + u.z + b.z), (_Float16)(v.w + u.w + b.w)};
  *(uint2*)(h1 + idx) = *(const uint2*)o;
}

// ---------- combine2: h2 = p0+p1+p2+p3 + b2 (fp32)  [2048][512]
__global__ __launch_bounds__(256)
void combine2(const float* __restrict__ P, const float* __restrict__ b2,
              float* __restrict__ h2) {
  const int idx = (blockIdx.x * 256 + threadIdx.x) * 4;
  const int col = idx & (N2q - 1);
  const size_t MN = (size_t)Mq * N2q;
  float4 s = *(const float4*)(b2 + col);
  #pragma unroll
  for (int z = 0; z < 4; ++z) {
    float4 v = *(const float4*)(P + (size_t)z * MN + idx);
    s.x += v.x; s.y += v.y; s.z += v.z; s.w += v.w;
  }
  *(float4*)(h2 + idx) = s;
}

// ---------- GEMM3 (fp32, exact) + fused loss: one wave per slot
__global__ __launch_bounds__(256)
void loss_kernel(const float* __restrict__ h2, const float* __restrict__ W3,
                 const float* __restrict__ b3, const float* __restrict__ labels,
                 float* __restrict__ acc) {
  const int tid = threadIdx.x, w = tid >> 6, lane = tid & 63;
  const int m = blockIdx.x * 4 + w;
  const float* hp = h2 + (size_t)m * N2q + lane * 8;
  float4 ha = *(const float4*)hp, hb = *(const float4*)(hp + 4);
  float h[8] = {ha.x, ha.y, ha.z, ha.w, hb.x, hb.y, hb.z, hb.w};
  float a[Lq];
  #pragma unroll
  for (int c = 0; c < Lq; ++c) a[c] = 0.f;
  #pragma unroll
  for (int j = 0; j < 8; ++j) {
    const float* wr = W3 + (size_t)(lane * 8 + j) * Lq;
    #pragma unroll
    for (int c = 0; c < Lq; ++c) a[c] = fmaf(h[j], wr[c], a[c]);
  }
  float logit = 0.f;
  #pragma unroll
  for (int c = 0; c < Lq; ++c) {
    float s = a[c];
    s += __shfl_xor(s, 32); s += __shfl_xor(s, 16); s += __shfl_xor(s, 8);
    s += __shfl_xor(s, 4);  s += __shfl_xor(s, 2);  s += __shfl_xor(s, 1);
    if (lane == c) logit = s;
  }
  const bool act = lane < Lq;
  float lab = 0.f;
  if (act) {
    logit += b3[lane];
    lab = labels[(size_t)m * Lq + lane];
  } else {
    logit = 0.f;
  }

  const unsigned long long validmask = __ballot(act && lab != -1.0f);
  const unsigned long long outmask   = __ballot(act && logit > 0.0f);
  const unsigned long long labmask   = __ballot(act && lab == 1.0f);
  const bool valid = (validmask != 0ULL);
  const int count_out = __popcll(outmask);
  const int count_lab = __popcll(labmask);

  float bce = 0.f;
  if (act && valid) {
    const float x = logit;
    bce = fmaxf(x, 0.f) + log1pf(expf(-fabsf(x))) - x * lab;
  }
  #pragma unroll
  for (int off = 32; off > 0; off >>= 1) bce += __shfl_xor(bce, off);

  if (lane == 0) {
    if (valid) {
      atomicAdd(&acc[0], bce);
      atomicAdd(&acc[1], 1.0f);
      const float d = (float)count_out - (float)count_lab;
      atomicAdd(&acc[2], d * d);
    }
    if (count_out == 1 && count_lab == 1) {
      const float po = (float)(__ffsll((long long)outmask) - 1);
      const float pl = (float)(__ffsll((long long)labmask) - 1);
      atomicAdd(&acc[3], 1.0f);
      const float dp = po - pl;
      atomicAdd(&acc[4], dp * dp);
    }
  }
}

__global__ void finalize_kernel(const float* __restrict__ acc,
                                float* __restrict__ out) {
  const float bce = acc[0] / (acc[1] * (float)Lq);
  const float cnt = 10.0f * acc[2] / (float)Mq;
  const float pos = (acc[3] > 0.f) ? 5.0f * acc[4] / fmaxf(acc[3], 1.0f) : 0.f;
  out[0] = bce + cnt + pos;
}

extern "C" void kernel_launch(void* const* d_in, const int* in_sizes, int n_in,
                              void* d_out, int out_size, void* d_ws, size_t ws_size,
                              hipStream_t stream) {
  const float* tok    = (const float*)d_in[0];
  const float* pool   = (const float*)d_in[1];
  const int*   npos   = (const int*)  d_in[2];
  const float* labels = (const float*)d_in[3];
  const float* W1     = (const float*)d_in[4];
  const float* b1     = (const float*)d_in[5];
  const float* W2     = (const float*)d_in[6];
  const float* b2     = (const float*)d_in[7];
  const float* W3     = (const float*)d_in[8];
  const float* b3     = (const float*)d_in[9];
  float* out = (float*)d_out;

  char* ws = (char*)d_ws;
  // layout (bytes): C2part overlays A1+C1part region (both dead by gemm2 time)
  _Float16* A1   = (_Float16*)(ws + 0x00000000);  // 6 MB  [2048][1536]
  float*    C2p  = (float*)   (ws + 0x00000000);  // 16 MB [4][2048][512]
  float*    C1p  = (float*)   (ws + 0x00600000);  // 16 MB [2][2048][1024]
  _Float16* W1T  = (_Float16*)(ws + 0x01600000);  // 3 MB  [1024][1536]
  _Float16* W2T  = (_Float16*)(ws + 0x01A00000);  // 1 MB  [512][1024]
  _Float16* h1   = (_Float16*)(ws + 0x01B00000);  // 4 MB  [2048][1024]
  float*    h2   = (float*)   (ws + 0x01F00000);  // 4 MB  [2048][512]
  float*    acc  = (float*)   (ws + 0x02300000);  // 32 B

  prep_a1<<<2048, 256, 0, stream>>>(tok, pool, npos, A1, acc);
  transpose_cvt<K1q, N1q><<<dim3(N1q / 64, K1q / 64), 256, 0, stream>>>(W1, W1T);
  transpose_cvt<N1q, N2q><<<dim3(N2q / 64, N1q / 64), 256, 0, stream>>>(W2, W2T);
  gemm_f16<K1q, 768, N1q><<<dim3(8, 16, 2), 256, 0, stream>>>(A1, W1T, C1p);
  combine1<<<2048, 256, 0, stream>>>(C1p, b1, h1);
  gemm_f16<N1q, 256, N2q><<<dim3(4, 16, 4), 256, 0, stream>>>(h1, W2T, C2p);
  combine2<<<1024, 256, 0, stream>>>(C2p, b2, h2);
  loss_kernel<<<512, 256, 0, stream>>>(h2, W3, b3, labels, acc);
  finalize_kernel<<<1, 1, 0, stream>>>(acc, out);
}

// Round 3
// 204.374 us; speedup vs baseline: 1.7586x; 1.2535x over previous
//
#include <hip/hip_runtime.h>
#include <cstddef>
#include <cstdint>

#define Mq   2048      // B*P
#define Lq   30
#define N1q  1024      // FH
#define N2q  512       // FH/2
#define K1q  1536      // 2*H
#define Hq   768
#define NBLK 512       // loss blocks

typedef float    f32x4 __attribute__((ext_vector_type(4)));
typedef _Float16 f16x8 __attribute__((ext_vector_type(8)));

#define GLD16(gptr, lptr) \
  __builtin_amdgcn_global_load_lds((const __attribute__((address_space(1))) void*)(gptr), \
                                   (__attribute__((address_space(3))) void*)(lptr), 16, 0, 0)

// ---------- prep: gather token rows + pooler -> A1 fp16 [2048][1536]
__global__ __launch_bounds__(256)
void prep_a1(const float* __restrict__ tok, const float* __restrict__ pool,
             const int* __restrict__ npos, _Float16* __restrict__ A1) {
  const int m = blockIdx.x;
  const int bI = m >> 5, p = m & 31;
  const int pos = npos[bI * 32 + p];
  const float* src1 = tok + ((size_t)bI * 512 + pos) * Hq;
  const float* src2 = pool + (size_t)bI * Hq;
  _Float16* dst = A1 + (size_t)m * K1q;
  for (int g = threadIdx.x; g < 384; g += 256) {
    const float* s = (g < 192) ? (src1 + g * 4) : (src2 + (g - 192) * 4);
    float4 v = *(const float4*)s;
    __align__(8) _Float16 o[4] = {(_Float16)v.x, (_Float16)v.y, (_Float16)v.z, (_Float16)v.w};
    *(uint2*)(dst + g * 4) = *(const uint2*)o;
  }
}

// ---------- transpose + convert: src f32 [K][N] -> dst f16 [N][K]
template<int K, int N>
__global__ __launch_bounds__(256)
void transpose_cvt(const float* __restrict__ src, _Float16* __restrict__ dst) {
  __shared__ float T[64][65];
  const int t = threadIdx.x;
  const int n0 = blockIdx.x * 64, k0 = blockIdx.y * 64;
  {
    const int kl = t >> 2, nc = (t & 3) * 16;
    const float* s = src + (size_t)(k0 + kl) * N + n0 + nc;
    float4 v0 = *(const float4*)s;
    float4 v1 = *(const float4*)(s + 4);
    float4 v2 = *(const float4*)(s + 8);
    float4 v3 = *(const float4*)(s + 12);
    T[nc + 0][kl] = v0.x; T[nc + 1][kl] = v0.y; T[nc + 2][kl] = v0.z; T[nc + 3][kl] = v0.w;
    T[nc + 4][kl] = v1.x; T[nc + 5][kl] = v1.y; T[nc + 6][kl] = v1.z; T[nc + 7][kl] = v1.w;
    T[nc + 8][kl] = v2.x; T[nc + 9][kl] = v2.y; T[nc +10][kl] = v2.z; T[nc +11][kl] = v2.w;
    T[nc +12][kl] = v3.x; T[nc +13][kl] = v3.y; T[nc +14][kl] = v3.z; T[nc +15][kl] = v3.w;
  }
  __syncthreads();
  {
    const int nl = t >> 2, kc = (t & 3) * 16;
    __align__(16) _Float16 tmp[16];
    #pragma unroll
    for (int i = 0; i < 16; ++i) tmp[i] = (_Float16)T[nl][kc + i];
    _Float16* d = dst + (size_t)(n0 + nl) * K + k0 + kc;
    *(uint4*)d       = *(const uint4*)tmp;
    *(uint4*)(d + 8) = *(const uint4*)(tmp + 8);
  }
}

// ---------- MFMA GEMM: A f16 [2048][KFULL] @ BT f16 [NC][KFULL] -> fp32 partials
template<int KFULL, int KSLICE, int NC>
__global__ __launch_bounds__(256)
void gemm_f16(const _Float16* __restrict__ A, const _Float16* __restrict__ BT,
              float* __restrict__ Cpart) {
  __shared__ _Float16 As[128 * 32];
  __shared__ _Float16 Bs[128 * 32];
  const int tid = threadIdx.x, w = tid >> 6, lane = tid & 63;
  const int n0 = blockIdx.x * 128, m0 = blockIdx.y * 128, z = blockIdx.z;
  const int ml = lane & 15, g4 = lane >> 4;
  const int wm = (w >> 1) * 64, wn = (w & 1) * 64;

  f32x4 acc[4][4];
  #pragma unroll
  for (int i = 0; i < 4; ++i)
    #pragma unroll
    for (int j = 0; j < 4; ++j)
      #pragma unroll
      for (int r = 0; r < 4; ++r) acc[i][j][r] = 0.f;

  const int rs0 = w * 32 + (lane >> 2);
  const int cl  = lane & 3;

  for (int it = 0; it < KSLICE / 32; ++it) {
    const int kt = z * KSLICE + it * 32;
    __syncthreads();
    #pragma unroll
    for (int t = 0; t < 2; ++t) {
      const int r  = rs0 + t * 16;
      const int cs = cl ^ ((r >> 1) & 3);
      GLD16(A  + (size_t)(m0 + r) * KFULL + kt + cs * 8, As + (w * 32 + t * 16) * 32);
      GLD16(BT + (size_t)(n0 + r) * KFULL + kt + cs * 8, Bs + (w * 32 + t * 16) * 32);
    }
    __syncthreads();
    f16x8 af[4], bf[4];
    #pragma unroll
    for (int i = 0; i < 4; ++i) {
      const int ar = wm + i * 16 + ml;
      af[i] = *(const f16x8*)(As + ar * 32 + ((g4 ^ ((ar >> 1) & 3)) << 3));
      const int br = wn + i * 16 + ml;
      bf[i] = *(const f16x8*)(Bs + br * 32 + ((g4 ^ ((br >> 1) & 3)) << 3));
    }
    #pragma unroll
    for (int i = 0; i < 4; ++i)
      #pragma unroll
      for (int j = 0; j < 4; ++j)
        acc[i][j] = __builtin_amdgcn_mfma_f32_16x16x32_f16(af[i], bf[j], acc[i][j], 0, 0, 0);
  }

  float* Cp = Cpart + (size_t)z * Mq * NC;
  #pragma unroll
  for (int i = 0; i < 4; ++i) {
    const int row0 = m0 + wm + i * 16 + g4 * 4;
    #pragma unroll
    for (int j = 0; j < 4; ++j) {
      const int col = n0 + wn + j * 16 + ml;
      #pragma unroll
      for (int r = 0; r < 4; ++r)
        Cp[(size_t)(row0 + r) * NC + col] = acc[i][j][r];
    }
  }
}

// ---------- combine1: h1 = f16(p0 + p1 + b1)   [2048][1024]
__global__ __launch_bounds__(256)
void combine1(const float* __restrict__ P, const float* __restrict__ b1,
              _Float16* __restrict__ h1) {
  const int idx = (blockIdx.x * 256 + threadIdx.x) * 4;
  const int col = idx & (N1q - 1);
  const size_t MN = (size_t)Mq * N1q;
  float4 v = *(const float4*)(P + idx);
  float4 u = *(const float4*)(P + MN + idx);
  float4 b = *(const float4*)(b1 + col);
  __align__(8) _Float16 o[4] = {
      (_Float16)(v.x + u.x + b.x), (_Float16)(v.y + u.y + b.y),
      (_Float16)(v.z + u.z + b.z), (_Float16)(v.w + u.w + b.w)};
  *(uint2*)(h1 + idx) = *(const uint2*)o;
}

// ---------- GEMM3 + fused loss, atomic-free.
// One wave per slot m. Lane -> (c = lane&31, khalf = lane>>5); each lane sums
// 256 k-terms (4 independent accumulators), shfl_xor(32) combines halves.
// Block reduces its 4 waves' scalars in LDS -> one 5-float partial per block.
__global__ __launch_bounds__(256)
void loss_kernel(const float* __restrict__ C2, const float* __restrict__ b2,
                 const float* __restrict__ W3, const float* __restrict__ b3,
                 const float* __restrict__ labels, float* __restrict__ part) {
  __shared__ float hrow[4][512];
  __shared__ float red[4][5];
  const int tid = threadIdx.x, w = tid >> 6, lane = tid & 63;
  const int m = blockIdx.x * 4 + w;
  const size_t MN2 = (size_t)Mq * N2q;

  // stage h row: h[k] = b2[k] + sum_z C2part[z][m][k]
  {
    const int k = lane * 8;
    float4 s0 = *(const float4*)(b2 + k);
    float4 s1 = *(const float4*)(b2 + k + 4);
    const float* cp = C2 + (size_t)m * N2q + k;
    #pragma unroll
    for (int z = 0; z < 4; ++z) {
      float4 v0 = *(const float4*)(cp + (size_t)z * MN2);
      float4 v1 = *(const float4*)(cp + (size_t)z * MN2 + 4);
      s0.x += v0.x; s0.y += v0.y; s0.z += v0.z; s0.w += v0.w;
      s1.x += v1.x; s1.y += v1.y; s1.z += v1.z; s1.w += v1.w;
    }
    *(float4*)&hrow[w][k]     = s0;
    *(float4*)&hrow[w][k + 4] = s1;
  }
  __syncthreads();   // uniform control flow; orders LDS write->read

  const int c  = lane & 31;
  const int kh = lane >> 5;
  float a0 = 0.f, a1 = 0.f, a2 = 0.f, a3 = 0.f;
  if (c < Lq) {
    const float* hp = hrow[w] + kh * 256;
    const float* wp = W3 + (size_t)(kh * 256) * Lq + c;
    #pragma unroll 4
    for (int i = 0; i < 256; i += 4) {
      a0 = fmaf(hp[i],     wp[(i)     * Lq], a0);
      a1 = fmaf(hp[i + 1], wp[(i + 1) * Lq], a1);
      a2 = fmaf(hp[i + 2], wp[(i + 2) * Lq], a2);
      a3 = fmaf(hp[i + 3], wp[(i + 3) * Lq], a3);
    }
  }
  float a = (a0 + a1) + (a2 + a3);
  a += __shfl_xor(a, 32);   // combine k-halves; both halves now hold full sum

  const bool act = lane < Lq;   // only lower-half lanes participate in masks
  float logit = 0.f, lab = 0.f;
  if (act) {
    logit = a + b3[lane];
    lab = labels[(size_t)m * Lq + lane];
  }

  const unsigned long long validmask = __ballot(act && lab != -1.0f);
  const unsigned long long outmask   = __ballot(act && logit > 0.0f);
  const unsigned long long labmask   = __ballot(act && lab == 1.0f);
  const bool valid = (validmask != 0ULL);
  const int count_out = __popcll(outmask);
  const int count_lab = __popcll(labmask);

  float bce = 0.f;
  if (act && valid) {
    const float x = logit;
    bce = fmaxf(x, 0.f) + log1pf(expf(-fabsf(x))) - x * lab;
  }
  bce += __shfl_xor(bce, 16); bce += __shfl_xor(bce, 8);
  bce += __shfl_xor(bce, 4);  bce += __shfl_xor(bce, 2);
  bce += __shfl_xor(bce, 1);  // lane 0 holds sum over c

  if (lane == 0) {
    float pb = 0.f, pv = 0.f, pc = 0.f, pe = 0.f, pp = 0.f;
    if (valid) {
      pb = bce; pv = 1.f;
      const float d = (float)count_out - (float)count_lab;
      pc = d * d;
    }
    if (count_out == 1 && count_lab == 1) {
      const float po = (float)(__ffsll((long long)outmask) - 1);
      const float pl = (float)(__ffsll((long long)labmask) - 1);
      pe = 1.f;
      const float dp = po - pl;
      pp = dp * dp;
    }
    red[w][0] = pb; red[w][1] = pv; red[w][2] = pc; red[w][3] = pe; red[w][4] = pp;
  }
  __syncthreads();
  if (tid < 5) {
    part[blockIdx.x * 5 + tid] =
        red[0][tid] + red[1][tid] + red[2][tid] + red[3][tid];
  }
}

// ---------- finalize: sum NBLK 5-float partials -> scalar loss
__global__ __launch_bounds__(256)
void finalize_kernel(const float* __restrict__ part, float* __restrict__ out) {
  __shared__ float red[32][5];
  const int t = threadIdx.x;
  if (t < 160) {
    const int j = t % 5, grp = t / 5;          // 32 groups
    float s = 0.f;
    for (int i = grp; i < NBLK; i += 32) s += part[i * 5 + j];
    red[grp][j] = s;
  }
  __syncthreads();
  if (t < 5) {
    float s = 0.f;
    #pragma unroll
    for (int g = 0; g < 32; ++g) s += red[g][t];
    red[0][t] = s;
  }
  __syncthreads();
  if (t == 0) {
    const float bce = red[0][0] / (red[0][1] * (float)Lq);
    const float cnt = 10.0f * red[0][2] / (float)Mq;
    const float pos = (red[0][3] > 0.f) ? 5.0f * red[0][4] / fmaxf(red[0][3], 1.0f) : 0.f;
    out[0] = bce + cnt + pos;
  }
}

extern "C" void kernel_launch(void* const* d_in, const int* in_sizes, int n_in,
                              void* d_out, int out_size, void* d_ws, size_t ws_size,
                              hipStream_t stream) {
  const float* tok    = (const float*)d_in[0];
  const float* pool   = (const float*)d_in[1];
  const int*   npos   = (const int*)  d_in[2];
  const float* labels = (const float*)d_in[3];
  const float* W1     = (const float*)d_in[4];
  const float* b1     = (const float*)d_in[5];
  const float* W2     = (const float*)d_in[6];
  const float* b2     = (const float*)d_in[7];
  const float* W3     = (const float*)d_in[8];
  const float* b3     = (const float*)d_in[9];
  float* out = (float*)d_out;

  char* ws = (char*)d_ws;
  // C2p overlays A1/C1p: both dead once gemm2 runs (gemm2 reads h1/W2T only).
  _Float16* A1   = (_Float16*)(ws + 0x00000000);  // 6 MB  [2048][1536]
  float*    C2p  = (float*)   (ws + 0x00000000);  // 16 MB [4][2048][512]
  float*    C1p  = (float*)   (ws + 0x00600000);  // 16 MB [2][2048][1024]
  _Float16* W1T  = (_Float16*)(ws + 0x01600000);  // 3 MB  [1024][1536]
  _Float16* W2T  = (_Float16*)(ws + 0x01A00000);  // 1 MB  [512][1024]
  _Float16* h1   = (_Float16*)(ws + 0x01B00000);  // 4 MB  [2048][1024]
  float*    part = (float*)   (ws + 0x01F00000);  // 10 KB [512][5]

  prep_a1<<<2048, 256, 0, stream>>>(tok, pool, npos, A1);
  transpose_cvt<K1q, N1q><<<dim3(N1q / 64, K1q / 64), 256, 0, stream>>>(W1, W1T);
  transpose_cvt<N1q, N2q><<<dim3(N2q / 64, N1q / 64), 256, 0, stream>>>(W2, W2T);
  gemm_f16<K1q, 768, N1q><<<dim3(8, 16, 2), 256, 0, stream>>>(A1, W1T, C1p);
  combine1<<<2048, 256, 0, stream>>>(C1p, b1, h1);
  gemm_f16<N1q, 256, N2q><<<dim3(4, 16, 4), 256, 0, stream>>>(h1, W2T, C2p);
  loss_kernel<<<NBLK, 256, 0, stream>>>(C2p, b2, W3, b3, labels, part);
  finalize_kernel<<<1, 256, 0, stream>>>(part, out);
}